// Round 7
// baseline (814.849 us; speedup 1.0000x reference)
//
#include <hip/hip_runtime.h>
#include <math.h>

// Problem constants
#define BATCH 32768
#define EMB   2048
#define KDIM  320      // 5*8*8
#define KACT  103      // ceil(0.05*2048)

// GEMM tiling: 1024 threads, 16 rows x 2048 cols per block, 2 cols/thread.
// acc[16][2]=32 VGPRs, A via uniform s_load (SGPRs), 8 waves/SIMD.
// r3 lesson: BM=8 main loop is latency-catastrophic (27.9% VALUBusy). Do not
// shrink. Session-header lesson: no manual B prefetch (reg cap). Epilogue
// ledger (r0..r6): radix-256 histogram ~38us beats LDS bisection (~87us,
// allocator remat) and global bisection (~130us, HBM spill). Keep radix.
#define BM 16
#define GTHREADS 1024
#define CIMG 16

// Radix histogram row stride (16B-aligned, != 0 mod 32 banks)
#define HSTRIDE 260

// ---------------------------------------------------------------------------
// Kernel 0: transpose fc_w (2048 x 320) -> WTP, k-PAIR-interleaved:
//   WTP[(k>>1)*2*EMB + n*2 + (k&1)] = W[n][k]
// so {W[2kp][n], W[2kp+1][n], W[2kp][n+1], W[2kp+1][n+1]} are 16 contiguous
// bytes -> the GEMM loads B for 2 k-steps x 2 cols in ONE dwordx4 (halves
// VMEM instr count, 16B/lane coalescing sweet spot).
// ---------------------------------------------------------------------------
__global__ __launch_bounds__(256) void transpose_w_kernel(const float* __restrict__ W,
                                                          float* __restrict__ WTP) {
  __shared__ float tile[32][33];
  const int k0 = blockIdx.x * 32;
  const int n0 = blockIdx.y * 32;
  const int tx = threadIdx.x;
  const int ty = threadIdx.y;
  for (int i = ty; i < 32; i += 8)
    tile[i][tx] = W[(size_t)(n0 + i) * KDIM + k0 + tx];
  __syncthreads();
  for (int i = ty; i < 32; i += 8) {
    const int k = k0 + i;
    const int n = n0 + tx;
    WTP[(size_t)(k >> 1) * (2 * EMB) + n * 2 + (k & 1)] = tile[tx][i];
  }
}

// ---------------------------------------------------------------------------
// Fused kernel (r7): r6 structure (verified, 600us) with the main loop's B
// stream switched to paired-k dwordx4 loads. FMA order per accumulator is
// unchanged (strictly ascending k) -> bit-identical z -> identical output.
// ---------------------------------------------------------------------------
__global__ __launch_bounds__(GTHREADS, 8) void fused_conv_gemm_topk(
    const float* __restrict__ x,
    const float* __restrict__ cw,
    const float* __restrict__ gamma,
    const float* __restrict__ beta,
    const float* __restrict__ mean,
    const float* __restrict__ var,
    float* __restrict__ HtW,            // A-tile write path
    const float* __restrict__ HtR,      // A-tile read path (same memory, fenced)
    const float* __restrict__ WTP,      // k-pair-interleaved W
    float* __restrict__ out) {
#pragma clang fp contract(off)
  __shared__ __attribute__((aligned(16))) float smem[17984];  // xs 12544 | hs 5440
  __shared__ float wv[45];
  __shared__ float inv_s[5], mu_s[5], be_s[5];
  __shared__ unsigned prefix_s[BM];
  __shared__ unsigned rank_s[BM];

  float* const xs = smem;                      // 16 imgs x 784 (conv phase)
  float* const hs = smem + 12544;              // 320 x 17 k-major staging
  unsigned* const histo = (unsigned*)smem;     // BM*HSTRIDE = 16.6 KB (epilogue)

  const int t    = threadIdx.x;
  const int lane = t & 63;
  const int w    = t >> 6;             // wave 0..15
  const int b0   = blockIdx.x * CIMG;

  // ==== phase 0: stage 16 images ==========================================
  {
    const float4* src = (const float4*)(x + (size_t)b0 * 784);
    float4* dst = (float4*)xs;
    for (int i = t; i < CIMG * 196; i += GTHREADS) dst[i] = src[i];
  }
  if (t < 45) wv[t] = cw[t];
  if (t < 5) {
    inv_s[t] = gamma[t] / sqrtf(var[t] + 1e-5f);  // IEEE div & sqrt
    mu_s[t] = mean[t];
    be_s[t] = beta[t];
  }
  __syncthreads();

  // ==== phase 1: conv+bn+relu+pool, one image per wave ====================
  {
    const int img = w;
    const float* xb = xs + img * 784;
    const int py = lane >> 3;
    const int px = lane & 7;

    float xr[5][5];
#pragma unroll
    for (int i = 0; i < 5; ++i)
#pragma unroll
      for (int j = 0; j < 5; ++j)
        xr[i][j] = xb[(3 * py + i) * 28 + 3 * px + j];

#pragma unroll
    for (int c = 0; c < 5; ++c) {
      float wr[9];
#pragma unroll
      for (int i = 0; i < 9; ++i) wr[i] = wv[c * 9 + i];
      const float inv = inv_s[c], mu = mu_s[c], be = be_s[c];
      float mx = -__builtin_huge_valf();
#pragma unroll
      for (int ry = 0; ry < 3; ++ry)
#pragma unroll
        for (int rx = 0; rx < 3; ++rx) {
          float s = 0.0f;
#pragma unroll
          for (int di = 0; di < 3; ++di)
#pragma unroll
            for (int dj = 0; dj < 3; ++dj)
              s = __builtin_fmaf(xr[ry + di][rx + dj], wr[di * 3 + dj], s);
          float t1 = s - mu;
          float t2 = t1 * inv;
          float t3 = t2 + be;
          mx = fmaxf(mx, t3);
        }
      hs[(c * 64 + lane) * 17 + img] = fmaxf(mx, 0.0f);
    }
  }
  __syncthreads();

  // ==== phase 2: A-tile -> global (coalesced; stays L2-hot) ===============
  {
    float* dst = HtW + (size_t)blockIdx.x * (KDIM * CIMG);
    for (int i = t; i < KDIM * CIMG; i += GTHREADS) {
      const int k = i >> 4;
      const int img = i & 15;
      dst[i] = hs[k * 17 + img];
    }
  }
  if (t < BM) { prefix_s[t] = 0u; rank_s[t] = KACT; }  // visible after next barrier
  __syncthreads();   // drains vmcnt -> A-tile visible in L2 for s_loads

  // ==== phase 3: GEMM main loop (paired-k B loads; FMA order unchanged) ===
  const int m0 = blockIdx.x * BM;
  const int nt = t * 2;

  float acc[BM][2];
#pragma unroll
  for (int m = 0; m < BM; ++m) {
    acc[m][0] = 0.0f;
    acc[m][1] = 0.0f;
  }

  const float* Ap  = HtR + (size_t)blockIdx.x * (KDIM * BM);  // A(k,m)=Ap[k*16+m]
  const float* wpp = WTP + (size_t)nt * 2;

#pragma unroll 4
  for (int kp = 0; kp < KDIM / 2; ++kp) {
    const float* ak = Ap + (size_t)kp * (2 * BM);
    float av0[BM], av1[BM];
#pragma unroll
    for (int m = 0; m < BM; ++m) av0[m] = ak[m];        // uniform -> s_load
#pragma unroll
    for (int m = 0; m < BM; ++m) av1[m] = ak[BM + m];
    // bb = {W[2kp][nt], W[2kp+1][nt], W[2kp][nt+1], W[2kp+1][nt+1]}
    const float4 bb = *(const float4*)(wpp + (size_t)kp * (2 * EMB));
#pragma unroll
    for (int m = 0; m < BM; ++m) {                      // k = 2kp
      acc[m][0] = __builtin_fmaf(av0[m], bb.x, acc[m][0]);
      acc[m][1] = __builtin_fmaf(av0[m], bb.z, acc[m][1]);
    }
#pragma unroll
    for (int m = 0; m < BM; ++m) {                      // k = 2kp+1
      acc[m][0] = __builtin_fmaf(av1[m], bb.y, acc[m][0]);
      acc[m][1] = __builtin_fmaf(av1[m], bb.w, acc[m][1]);
    }
  }
  __syncthreads();  // conv LDS dead; prefix/rank init visible; histo region free

  // ==== phase 4: radix-256 select of the KACT-th largest per row ==========
  for (int pass = 0; pass < 4; ++pass) {
    const int shift = 24 - pass * 8;
    for (int i = t; i < BM * HSTRIDE; i += GTHREADS) histo[i] = 0u;
    unsigned pref[BM];
#pragma unroll
    for (int m = 0; m < BM; ++m) pref[m] = prefix_s[m];
    __syncthreads();
#pragma unroll
    for (int m = 0; m < BM; ++m) {
#pragma unroll
      for (int j = 0; j < 2; ++j) {
        unsigned u = __float_as_uint(acc[m][j]);
        u = (u & 0x80000000u) ? ~u : (u | 0x80000000u);  // ascending order map
        const bool in = (pass == 0) || ((u >> (shift + 8)) == pref[m]);
        if (in) atomicAdd(&histo[m * HSTRIDE + ((u >> shift) & 255u)], 1u);
      }
    }
    __syncthreads();
    // Scan: wave w handles row w. Lane l covers bins [4l,4l+4); suffix-sum =
    // counts-above. Exactly one lane satisfies the rank bracket.
    {
      const int m = w;
      const unsigned rank = rank_s[m];
      const uint4 c = *(const uint4*)(histo + m * HSTRIDE + lane * 4);
      const unsigned s = c.x + c.y + c.z + c.w;
      unsigned suf = s;
#pragma unroll
      for (int off = 1; off < 64; off <<= 1) {
        const unsigned o = __shfl_down(suf, off);
        if (lane + off < 64) suf += o;
      }
      const unsigned above = suf - s;  // counts in bins > 4*lane+3
      if (above < rank && rank <= suf) {
        unsigned bin, newr;
        if (above + c.w >= rank)                    { bin = lane * 4 + 3; newr = rank - above; }
        else if (above + c.w + c.z >= rank)         { bin = lane * 4 + 2; newr = rank - above - c.w; }
        else if (above + c.w + c.z + c.y >= rank)   { bin = lane * 4 + 1; newr = rank - above - c.w - c.z; }
        else                                        { bin = lane * 4 + 0; newr = rank - above - c.w - c.z - c.y; }
        prefix_s[m] = (prefix_s[m] << 8) | bin;
        rank_s[m] = newr;
      }
    }
    __syncthreads();
  }

  // prefix_s[m] now holds the exact uint-mapped 103rd-largest value
  unsigned thr[BM];
#pragma unroll
  for (int m = 0; m < BM; ++m) thr[m] = prefix_s[m];

#pragma unroll
  for (int m = 0; m < BM; ++m) {
    float2 o;
#pragma unroll
    for (int j = 0; j < 2; ++j) {
      unsigned u = __float_as_uint(acc[m][j]);
      u = (u & 0x80000000u) ? ~u : (u | 0x80000000u);
      ((float*)&o)[j] = (u >= thr[m]) ? 1.0f : 0.0f;  // tie semantics: z >= topv[:,-1]
    }
    *(float2*)(out + (size_t)(m0 + m) * EMB + nt) = o;
  }
}

// ---------------------------------------------------------------------------
extern "C" void kernel_launch(void* const* d_in, const int* in_sizes, int n_in,
                              void* d_out, int out_size, void* d_ws, size_t ws_size,
                              hipStream_t stream) {
  const float* x      = (const float*)d_in[0];
  const float* conv_w = (const float*)d_in[1];
  const float* gamma  = (const float*)d_in[2];
  const float* beta   = (const float*)d_in[3];
  const float* mean   = (const float*)d_in[4];
  const float* var    = (const float*)d_in[5];
  const float* fc_w   = (const float*)d_in[6];
  float* out = (float*)d_out;

  // workspace: Ht tile-major (2048 tiles x 320 x 16 f32 = 40 MB) | WTP (320x2048)
  float* Ht  = (float*)d_ws;
  float* WTP = (float*)d_ws + (size_t)KDIM * BATCH;

  transpose_w_kernel<<<dim3(KDIM / 32, EMB / 32), dim3(32, 8), 0, stream>>>(fc_w, WTP);
  fused_conv_gemm_topk<<<BATCH / CIMG, GTHREADS, 0, stream>>>(
      x, conv_w, gamma, beta, mean, var, Ht, Ht, WTP, out);
}